// Round 6
// baseline (2079.009 us; speedup 1.0000x reference)
//
#include <hip/hip_runtime.h>
#include <math.h>

// Problem constants
#define NN 256
#define AD 32
#define BB 64
#define TT 128
#define KJ0 (-0.1f)
#define KJ1 (0.1f)
#define KALPHA 0.15f
#define BUMP_OFF (BB*TT*NN)   // 2097152 floats; d_out = [r_history | bump]

// LDS layout (float offsets). Total 38864 floats = 155456 B < 160 KiB.
// 155KB/WG forces 1 WG/CU; grid=256 WGs on 256 CUs -> all co-resident under
// ANY dispatch order (no cooperative launch needed -> graph-capture-safe).
// r row stride 268 floats: 4-row (bg) stride = 1072 ≡ 16 mod 32 banks -> worst
// 2-way LDS aliasing (free, m136); 264 gave 4-row stride ≡ 0 -> 4-way conflict.
#define RSTR 268
#define LDS_WM   0        // W_main [i:128][ks:64][m:4] = 32768 (Wa slice, permuted)
#define LDS_WW   32768    // W_wo   [n:256][m:4] = 1024  (J1-prescaled Wo slice)
#define LDS_RL   33792    // r      [b:16][RSTR]  (phys n = n + 4*(n>=128) gap)
#define LDS_CF   38080    // coef   [a:32][b:16]
#define LDS_RED  38592    // reduce [w:4][l:64]
#define LDS_SUMR 38848    // sum_n r[b,n] per local b (16)
#define LDS_FLOATS 38864

// Per-bt barrier state: 4 groups x 64 uints (256B): [0]=count, [32]=phase
// (count and phase in separate 128B cache lines; groups in separate lines).
#define BAR_STRIDE 64

__global__ void __launch_bounds__(256) ring_init(unsigned* bar) {
  bar[threadIdx.x] = 0u;   // zero all 4 groups (4*64 = 256 uints)
}

// Group barrier over the 64 WGs sharing one bt (the only WGs whose r rows we
// consume). Agent-scope atomics handle cross-XCD visibility (release -> L2
// writeback, acquire -> invalidate). Spin BOUNDED (1 ms ≈ 500-1000x expected
// 1-2 us) so a residency failure degrades to a fast wrong answer, not a hang.
__device__ __forceinline__ void group_barrier(unsigned* g, unsigned phase) {
  __syncthreads();   // all lanes' r_new stores issued before thread 0 releases
  if (threadIdx.x == 0) {
    unsigned old = __hip_atomic_fetch_add(&g[0], 1u, __ATOMIC_ACQ_REL, __HIP_MEMORY_SCOPE_AGENT);
    if (old == 63u) {
      __hip_atomic_store(&g[0], 0u, __ATOMIC_RELAXED, __HIP_MEMORY_SCOPE_AGENT);
      __hip_atomic_store(&g[32], phase, __ATOMIC_RELEASE, __HIP_MEMORY_SCOPE_AGENT);
    } else {
      const unsigned long long t0 = __builtin_amdgcn_s_memrealtime();  // 100 MHz
      while (__hip_atomic_load(&g[32], __ATOMIC_RELAXED, __HIP_MEMORY_SCOPE_AGENT) < phase) {
        __builtin_amdgcn_s_sleep(2);
        if (__builtin_amdgcn_s_memrealtime() - t0 > 100000ull) break;  // 1 ms cap
      }
      (void)__hip_atomic_load(&g[32], __ATOMIC_ACQUIRE, __HIP_MEMORY_SCOPE_AGENT);
    }
  }
  __syncthreads();
}

// 256 WGs: bid = bt*64 + mt. bt in 0..3 -> 16 batches; mt in 0..63 -> 4 outputs.
// 256 thr: wave wv=tid>>6, lane ln=tid&63; bg=ln&3 (b-quad), ks=wv*16+(ln>>2) (k-slice).
// Thread k-slice = action a=ks>>1, n-half = (ks&1)*128 .. +128  (single coef per slice).
__global__ void __launch_bounds__(256) ring_main(const float* __restrict__ act,
                                                 const float* __restrict__ Wo,
                                                 const float* __restrict__ Wa,
                                                 float* __restrict__ out,
                                                 float* __restrict__ rbuf,
                                                 unsigned* __restrict__ bar) {
  extern __shared__ float sm[];
  const int tid = threadIdx.x;
  const int bid = blockIdx.x;
  const int bt = bid >> 6;
  const int mt = bid & 63;
  const int wv = tid >> 6;
  const int ln = tid & 63;
  const int bg = ln & 3;
  const int ks = wv*16 + (ln >> 2);
  const int a_idx = ks >> 1;
  const int half = ks & 1;
  unsigned* barg = bar + bt*BAR_STRIDE;

  // ---- one-time: gather Wa slice into LDS, layout [i][ks][m] so the hot-loop
  // wave read (lanes = 16 ks) is contiguous & conflict-free ----
  for (int j = 0; j < 32; ++j) {
    const int flat = j*256 + tid;            // 0..8191 = i*64 + kk
    const int i = flat >> 6, kk = flat & 63;
    const int a = kk >> 1, n = ((kk & 1) << 7) + i;
    const float4 w = *(const float4*)(Wa + ((a<<8) + n)*NN + (mt<<2));
    *(float4*)(&sm[LDS_WM + (flat<<2)]) = w;
  }
  { // Wo slice, pre-scaled by J1
    const float4 w = *(const float4*)(Wo + tid*NN + (mt<<2));
    float4 s; s.x = w.x*KJ1; s.y = w.y*KJ1; s.z = w.z*KJ1; s.w = w.w*KJ1;
    *(float4*)(&sm[LDS_WW + (tid<<2)]) = s;
  }

  // ---- t=0 state: initial bump (identical for all batches), computed locally ----
  {
    const int b = tid >> 4, c = tid & 15;
    float v0[16]; float ss = 0.f, sv = 0.f;
    const float width = 25.6f;
    const float denom = 2.0f*width*width;
    #pragma unroll
    for (int u = 0; u < 16; ++u) {
      const float fn = (float)(c*16 + u);
      const float d = fabsf(fn - 128.0f);
      const float dist = fminf(d, 256.0f - d);
      const float e = expf(-(dist*dist)/denom);
      v0[u] = e; ss += e*e; sv += e;
    }
    ss += __shfl_xor(ss,8); ss += __shfl_xor(ss,4); ss += __shfl_xor(ss,2); ss += __shfl_xor(ss,1);
    sv += __shfl_xor(sv,8); sv += __shfl_xor(sv,4); sv += __shfl_xor(sv,2); sv += __shfl_xor(sv,1);
    const float inv = 1.0f/sqrtf(ss);
    float* dst = &sm[LDS_RL] + b*RSTR + c*16 + ((c>=8)?4:0);
    #pragma unroll
    for (int u = 0; u < 16; ++u) dst[u] = v0[u]*inv;
    if (c == 0) sm[LDS_SUMR + b] = sv*inv;
  }

  int par = 0;
  for (int t = 0; t < TT; ++t) {
    // ---- stage r from global (t>0) + per-b row sums ----
    if (t > 0) {
      const int b = tid >> 4, c = tid & 15;
      const float* src = rbuf + par*(BB*NN) + (bt*16 + b)*NN + c*16;
      const float4 x0 = ((const float4*)src)[0];
      const float4 x1 = ((const float4*)src)[1];
      const float4 x2 = ((const float4*)src)[2];
      const float4 x3 = ((const float4*)src)[3];
      float* dst = &sm[LDS_RL] + b*RSTR + c*16 + ((c>=8)?4:0);
      ((float4*)dst)[0]=x0; ((float4*)dst)[1]=x1; ((float4*)dst)[2]=x2; ((float4*)dst)[3]=x3;
      float s = x0.x+x0.y+x0.z+x0.w + x1.x+x1.y+x1.z+x1.w
              + x2.x+x2.y+x2.z+x2.w + x3.x+x3.y+x3.z+x3.w;
      s += __shfl_xor(s,8); s += __shfl_xor(s,4); s += __shfl_xor(s,2); s += __shfl_xor(s,1);
      if (c == 0) sm[LDS_SUMR + b] = s;
    }
    // ---- stage action coefficients [a][b16] ----
    {
      const int b0 = tid >> 5, aa = tid & 31;
      sm[LDS_CF + aa*16 + b0]     = act[(bt*16 + b0)*(TT*AD) + t*AD + aa];
      sm[LDS_CF + aa*16 + b0 + 8] = act[(bt*16 + b0 + 8)*(TT*AD) + t*AD + aa];
    }
    __syncthreads();

    // ---- compute: acc[v][m] partials for 4b x 4m tile ----
    float acc[4][4];
    #pragma unroll
    for (int v = 0; v < 4; ++v) { acc[v][0]=0.f; acc[v][1]=0.f; acc[v][2]=0.f; acc[v][3]=0.f; }

    // Wo pass (coef J1 pre-baked): 4 n's per thread, stride-64 interleave
    #pragma unroll
    for (int u = 0; u < 4; ++u) {
      const int n = u*64 + ks;
      const float4 w = *(const float4*)&sm[LDS_WW + (n<<2)];
      const int np = n + ((u >= 2) ? 4 : 0);
      #pragma unroll
      for (int v = 0; v < 4; ++v) {
        const float rv = sm[LDS_RL + (bg*4+v)*RSTR + np];
        acc[v][0] += rv*w.x; acc[v][1] += rv*w.y; acc[v][2] += rv*w.z; acc[v][3] += rv*w.w;
      }
    }

    // Main pass: this thread's (a, half) slice of 128 n, one coef at the end
    float pacc[4][4];
    #pragma unroll
    for (int v = 0; v < 4; ++v) { pacc[v][0]=0.f; pacc[v][1]=0.f; pacc[v][2]=0.f; pacc[v][3]=0.f; }
    const float* wp  = &sm[LDS_WM + ks*4];
    const float* rp0 = &sm[LDS_RL + (bg*4+0)*RSTR + 132*half];
    const float* rp1 = rp0 + RSTR;
    const float* rp2 = rp1 + RSTR;
    const float* rp3 = rp2 + RSTR;
    #pragma unroll 2
    for (int i = 0; i < 128; i += 4) {
      const float4 w0 = *(const float4*)(wp + (i  )*256);
      const float4 w1 = *(const float4*)(wp + (i+1)*256);
      const float4 w2 = *(const float4*)(wp + (i+2)*256);
      const float4 w3 = *(const float4*)(wp + (i+3)*256);
      const float4 ra = *(const float4*)(rp0 + i);
      const float4 rb = *(const float4*)(rp1 + i);
      const float4 rc = *(const float4*)(rp2 + i);
      const float4 rd = *(const float4*)(rp3 + i);
      #pragma unroll
      for (int u = 0; u < 4; ++u) {
        const float4 w = (u==0)?w0:((u==1)?w1:((u==2)?w2:w3));
        const float r0v = (u==0)?ra.x:((u==1)?ra.y:((u==2)?ra.z:ra.w));
        const float r1v = (u==0)?rb.x:((u==1)?rb.y:((u==2)?rb.z:rb.w));
        const float r2v = (u==0)?rc.x:((u==1)?rc.y:((u==2)?rc.z:rc.w));
        const float r3v = (u==0)?rd.x:((u==1)?rd.y:((u==2)?rd.z:rd.w));
        pacc[0][0] += r0v*w.x; pacc[0][1] += r0v*w.y; pacc[0][2] += r0v*w.z; pacc[0][3] += r0v*w.w;
        pacc[1][0] += r1v*w.x; pacc[1][1] += r1v*w.y; pacc[1][2] += r1v*w.z; pacc[1][3] += r1v*w.w;
        pacc[2][0] += r2v*w.x; pacc[2][1] += r2v*w.y; pacc[2][2] += r2v*w.z; pacc[2][3] += r2v*w.w;
        pacc[3][0] += r3v*w.x; pacc[3][1] += r3v*w.y; pacc[3][2] += r3v*w.z; pacc[3][3] += r3v*w.w;
      }
    }
    #pragma unroll
    for (int v = 0; v < 4; ++v) {
      const float cva = sm[LDS_CF + a_idx*16 + bg*4 + v];
      acc[v][0] += cva*pacc[v][0]; acc[v][1] += cva*pacc[v][1];
      acc[v][2] += cva*pacc[v][2]; acc[v][3] += cva*pacc[v][3];
    }

    // ---- narrowing butterfly over the 16 k-lanes sharing this bg (lane bits 2..5) ----
    float vals[16];
    #pragma unroll
    for (int v = 0; v < 4; ++v) { vals[v*4+0]=acc[v][0]; vals[v*4+1]=acc[v][1];
                                  vals[v*4+2]=acc[v][2]; vals[v*4+3]=acc[v][3]; }
    { const bool hi = (ln & 32) != 0;
      #pragma unroll
      for (int j = 0; j < 8; ++j) { const float kp = hi?vals[j+8]:vals[j], sd = hi?vals[j]:vals[j+8];
        vals[j] = kp + __shfl_xor(sd, 32); } }
    { const bool hi = (ln & 16) != 0;
      #pragma unroll
      for (int j = 0; j < 4; ++j) { const float kp = hi?vals[j+4]:vals[j], sd = hi?vals[j]:vals[j+4];
        vals[j] = kp + __shfl_xor(sd, 16); } }
    { const bool hi = (ln & 8) != 0;
      #pragma unroll
      for (int j = 0; j < 2; ++j) { const float kp = hi?vals[j+2]:vals[j], sd = hi?vals[j]:vals[j+2];
        vals[j] = kp + __shfl_xor(sd, 8); } }
    { const bool hi = (ln & 4) != 0;
      { const float kp = hi?vals[1]:vals[0], sd = hi?vals[0]:vals[1];
        vals[0] = kp + __shfl_xor(sd, 4); } }
    sm[LDS_RED + wv*64 + ln] = vals[0];
    __syncthreads();

    // ---- finalize: wave 0's 64 lanes = the WG's 64 outputs ----
    if (wv == 0) {
      const float tot = sm[LDS_RED+ln] + sm[LDS_RED+64+ln]
                      + sm[LDS_RED+128+ln] + sm[LDS_RED+192+ln];
      const int j = (((ln>>5)&1)<<3)|(((ln>>4)&1)<<2)|(((ln>>3)&1)<<1)|((ln>>2)&1);
      const int v = j >> 2, m = j & 3;
      const int b = (ln & 3)*4 + v;
      const int mm = (mt<<2) + m;
      const float rec  = tot + KJ0 * sm[LDS_SUMR + b];
      const float rold = sm[LDS_RL + b*RSTR + mm + ((mm>=128)?4:0)];
      const float rnew = (1.0f-KALPHA)*rold + KALPHA*fmaxf(rec, 0.0f);
      const int bgl = bt*16 + b;
      rbuf[(par^1)*(BB*NN) + bgl*NN + mm] = rnew;
      out[BUMP_OFF + (bgl*TT + t)*NN + mm] = rnew;
    }
    if (t < TT-1) group_barrier(barg, (unsigned)(t+1));
    par ^= 1;
  }
}

// Epilogue: Wd7[n,m]=cos(2pi(n-m)/N) is rank-2 -> r_delta7 = C*cos_m + S*sin_m.
__global__ void __launch_bounds__(256) ring_epi(float* out) {
  const int b = blockIdx.x >> 7, t = blockIdx.x & 127;
  const int n = threadIdx.x;
  const int wv = threadIdx.x >> 6, ln = threadIdx.x & 63;
  __shared__ float l[12];
  const float v = out[BUMP_OFF + (b*TT + t)*NN + n];
  const float ang = (float)n * (6.283185307179586f/256.0f);
  const float cn = cosf(ang), sn = sinf(ang);
  float pc = v*cn, ps = v*sn;
  #pragma unroll
  for (int m = 32; m >= 1; m >>= 1) { pc += __shfl_xor(pc, m); ps += __shfl_xor(ps, m); }
  if (ln == 0) { l[wv] = pc; l[4+wv] = ps; }
  __syncthreads();
  const float C = l[0]+l[1]+l[2]+l[3];
  const float S = l[4]+l[5]+l[6]+l[7];
  const float d7 = C*cn + S*sn;
  float mx = d7;
  #pragma unroll
  for (int m = 32; m >= 1; m >>= 1) mx = fmaxf(mx, __shfl_xor(mx, m));
  if (ln == 0) l[8+wv] = mx;
  __syncthreads();
  mx = fmaxf(fmaxf(l[8], l[9]), fmaxf(l[10], l[11]));
  out[(b*TT + t)*NN + n] = d7/mx;
}

extern "C" void kernel_launch(void* const* d_in, const int* in_sizes, int n_in,
                              void* d_out, int out_size, void* d_ws, size_t ws_size,
                              hipStream_t stream) {
  const float* act = (const float*)d_in[0];   // [64,128,32]
  const float* Wo  = (const float*)d_in[1];   // [256,256]
  const float* Wa  = (const float*)d_in[2];   // [32,256,256]
  float* outp = (float*)d_out;                // [r_history | bump], 4194304 f32
  float* rbuf = (float*)d_ws;                 // 2 x 64x256 f32 double buffer
  unsigned* bar = (unsigned*)((char*)d_ws + 2*BB*NN*sizeof(float));  // 4 groups x 64 uints

  hipLaunchKernelGGL(ring_init, dim3(1), dim3(256), 0, stream, bar);

  // Host-side, stream-free, idempotent: needed for 155KB dynamic LDS. Set on
  // the correctness call; harmless no-op effect under graph capture.
  (void)hipFuncSetAttribute(reinterpret_cast<const void*>(ring_main),
                            hipFuncAttributeMaxDynamicSharedMemorySize, LDS_FLOATS*4);

  // Plain launch (graph-capture-safe). Co-residency by construction:
  // 155KB LDS -> 1 WG/CU, grid=256 = #CUs; each barrier group needs only
  // its own 64 WGs resident (weaker than full-grid residency).
  hipLaunchKernelGGL(ring_main, dim3(256), dim3(256), LDS_FLOATS*4, stream,
                     act, Wo, Wa, outp, rbuf, bar);

  hipLaunchKernelGGL(ring_epi, dim3(BB*TT), dim3(256), 0, stream, outp);
}

// Round 8
// 1699.364 us; speedup vs baseline: 1.2234x; 1.2234x over previous
//
#include <hip/hip_runtime.h>
#include <math.h>

// Problem constants
#define NN 256
#define AD 32
#define BB 64
#define TT 128
#define KJ0 (-0.1f)
#define KJ1 (0.1f)
#define KALPHA 0.15f
#define BUMP_OFF (BB*TT*NN)   // 2097152 floats; d_out = [r_history | bump]

// LDS layout (float offsets). Total 39888 floats = 159552 B < 160 KiB.
// 1 WG/CU (LDS-forced), 1024 threads = 16 waves = 4 waves/SIMD for latency
// hiding (round-6 counters: 1 wave/SIMD gave VALUBusy 21%, latency-bound).
// r physical index: phys(n) = n + (n>>5)*4 (4-float pad per 32-block).
// Bank audit: r b128 reads = 32 unique addrs, each bank serves exactly 4
// dwords = 4 cyc = structural minimum (no excess conflict); W reads 2 cyc min.
#define RSTR 284
#define LDS_WM   0        // W_main [i:32][ks:256][m:4] = 32768 (Wa slices)
#define LDS_WW   32768    // W_wo   [n:256][m:4] = 1024  (J1-prescaled Wo)
#define LDS_RL   33792    // r      [b:16][RSTR] = 4544
#define LDS_CF   38336    // coef   [a:32][b:16] = 512
#define LDS_RED  38848    // reduce [w:16][l:64] = 1024
#define LDS_SUMR 39872    // sum_n r[b,n] per local b (16)
#define LDS_FLOATS 39888

// Per-bt barrier state: 4 groups x 64 uints: [0]=count, [32]=phase.
#define BAR_STRIDE 64

__global__ void __launch_bounds__(256) ring_init(unsigned* bar) {
  bar[threadIdx.x] = 0u;   // zero all 4 groups
}

// Group barrier over the 64 WGs sharing one bt (the only producers of the r
// rows we consume). Agent-scope atomics: release -> L2 writeback, acquire ->
// invalidate (mechanism validated: round-6 run passed). Spin BOUNDED at 10 ms:
// ~40x margin over the worst observed profiled-replay barrier wait (~260 us,
// from round-6's 32.8 ms perturbed dispatch), so legitimate slow replays are
// never truncated; residency failure = fast wrong answer, never a hang.
__device__ __forceinline__ void group_barrier(unsigned* g, unsigned phase) {
  __syncthreads();   // all waves' r_new stores complete before thread 0 releases
  if (threadIdx.x == 0) {
    unsigned old = __hip_atomic_fetch_add(&g[0], 1u, __ATOMIC_ACQ_REL, __HIP_MEMORY_SCOPE_AGENT);
    if (old == 63u) {
      __hip_atomic_store(&g[0], 0u, __ATOMIC_RELAXED, __HIP_MEMORY_SCOPE_AGENT);
      __hip_atomic_store(&g[32], phase, __ATOMIC_RELEASE, __HIP_MEMORY_SCOPE_AGENT);
    } else {
      const unsigned long long t0 = __builtin_amdgcn_s_memrealtime();  // 100 MHz
      while (__hip_atomic_load(&g[32], __ATOMIC_RELAXED, __HIP_MEMORY_SCOPE_AGENT) < phase) {
        __builtin_amdgcn_s_sleep(2);
        if (__builtin_amdgcn_s_memrealtime() - t0 > 1000000ull) break;  // 10 ms cap
      }
      (void)__hip_atomic_load(&g[32], __ATOMIC_ACQUIRE, __HIP_MEMORY_SCOPE_AGENT);
    }
  }
  __syncthreads();
}

// 256 WGs: bid = bt*64 + mt (bt: 16 batches, mt: 4 outputs). 1024 threads:
// wv=tid>>6 (16 waves), ln=tid&63; bg=ln&3 (b-quad), ks=wv*16+(ln>>2) in
// 0..255: action a=ks>>3, n-slice [sub*32, sub*32+32), sub=ks&7 -> one action
// coefficient per thread slice, applied once after the inner loop.
__global__ void __launch_bounds__(1024) ring_main(const float* __restrict__ act,
                                                  const float* __restrict__ Wo,
                                                  const float* __restrict__ Wa,
                                                  float* __restrict__ out,
                                                  unsigned* __restrict__ bar) {
  extern __shared__ float sm[];
  const int tid = threadIdx.x;
  const int bid = blockIdx.x;
  const int bt = bid >> 6;
  const int mt = bid & 63;
  const int wv = tid >> 6;
  const int ln = tid & 63;
  const int bg = ln & 3;
  const int ks = wv*16 + (ln >> 2);     // 0..255
  const int a_idx = ks >> 3;
  const int sub = ks & 7;
  unsigned* barg = bar + bt*BAR_STRIDE;

  // ---- one-time: gather Wa slices, layout [i:32][ks:256][m:4] so the wave's
  // 16 consecutive ks read 256 contiguous bytes (conflict-free) ----
  #pragma unroll
  for (int j = 0; j < 8; ++j) {
    const int flat = j*1024 + tid;      // = i*256 + kk
    const int i = flat >> 8, kk = flat & 255;
    const int a = kk >> 3, n = ((kk & 7) << 5) + i;
    const float4 w = *(const float4*)(Wa + (a*NN + n)*NN + (mt<<2));
    *(float4*)(&sm[LDS_WM + (flat<<2)]) = w;
  }
  if (tid < 256) { // Wo slice, pre-scaled by J1
    const float4 w = *(const float4*)(Wo + tid*NN + (mt<<2));
    float4 s; s.x = w.x*KJ1; s.y = w.y*KJ1; s.z = w.z*KJ1; s.w = w.w*KJ1;
    *(float4*)(&sm[LDS_WW + (tid<<2)]) = s;
  }

  // ---- t=0 state: initial bump (identical for all batches); wave wv owns b=wv ----
  {
    const int c = ln;
    float v0[4]; float ss = 0.f, sv = 0.f;
    const float denom = 2.0f*25.6f*25.6f;
    #pragma unroll
    for (int u = 0; u < 4; ++u) {
      const float fn = (float)(c*4 + u);
      const float d = fabsf(fn - 128.0f);
      const float dist = fminf(d, 256.0f - d);
      const float e = expf(-(dist*dist)/denom);
      v0[u] = e; ss += e*e; sv += e;
    }
    ss += __shfl_xor(ss,32); ss += __shfl_xor(ss,16); ss += __shfl_xor(ss,8);
    ss += __shfl_xor(ss,4);  ss += __shfl_xor(ss,2);  ss += __shfl_xor(ss,1);
    sv += __shfl_xor(sv,32); sv += __shfl_xor(sv,16); sv += __shfl_xor(sv,8);
    sv += __shfl_xor(sv,4);  sv += __shfl_xor(sv,2);  sv += __shfl_xor(sv,1);
    const float inv = 1.0f/sqrtf(ss);
    float4 o; o.x = v0[0]*inv; o.y = v0[1]*inv; o.z = v0[2]*inv; o.w = v0[3]*inv;
    *(float4*)(&sm[LDS_RL + wv*RSTR + (c<<2) + ((c>>3)<<2)]) = o;  // phys(4c)
    if (c == 0) sm[LDS_SUMR + wv] = sv*inv;
  }

  for (int t = 0; t < TT; ++t) {
    // ---- stage r for t>0: wave wv stages batch row b=wv from out[t-1] ----
    if (t > 0) {
      const float* src = out + BUMP_OFF + (((bt*16 + wv)*TT) + (t-1))*NN + (ln<<2);
      const float4 x = *(const float4*)src;
      *(float4*)(&sm[LDS_RL + wv*RSTR + (ln<<2) + ((ln>>3)<<2)]) = x;
      float s = x.x + x.y + x.z + x.w;
      s += __shfl_xor(s,32); s += __shfl_xor(s,16); s += __shfl_xor(s,8);
      s += __shfl_xor(s,4);  s += __shfl_xor(s,2);  s += __shfl_xor(s,1);
      if (ln == 0) sm[LDS_SUMR + wv] = s;
    }
    // ---- stage action coefficients [a][b16] ----
    if (tid < 512) {
      const int b0 = tid >> 5, aa = tid & 31;
      sm[LDS_CF + aa*16 + b0] = act[(bt*16 + b0)*(TT*AD) + t*AD + aa];
    }
    __syncthreads();

    // ---- compute acc[v][m] for this thread's 4b x 4m tile ----
    float acc[4][4];
    #pragma unroll
    for (int v = 0; v < 4; ++v) { acc[v][0]=0.f; acc[v][1]=0.f; acc[v][2]=0.f; acc[v][3]=0.f; }

    // Wo pass (J1 pre-baked): single n = ks per thread
    {
      const float4 w = *(const float4*)&sm[LDS_WW + (ks<<2)];
      const int np = ks + ((ks>>5)<<2);   // phys(ks)
      #pragma unroll
      for (int v = 0; v < 4; ++v) {
        const float rv = sm[LDS_RL + ((bg<<2)+v)*RSTR + np];
        acc[v][0] += rv*w.x; acc[v][1] += rv*w.y; acc[v][2] += rv*w.z; acc[v][3] += rv*w.w;
      }
    }

    // Main pass: 32-n slice of action a_idx; coef applied once at the end
    float pacc[4][4];
    #pragma unroll
    for (int v = 0; v < 4; ++v) { pacc[v][0]=0.f; pacc[v][1]=0.f; pacc[v][2]=0.f; pacc[v][3]=0.f; }
    const float* wp  = &sm[LDS_WM + (ks<<2)];          // stride 1024 per i
    const float* rp0 = &sm[LDS_RL + (bg<<2)*RSTR + sub*36];  // phys(sub*32)=36*sub
    const float* rp1 = rp0 + RSTR;
    const float* rp2 = rp1 + RSTR;
    const float* rp3 = rp2 + RSTR;
    #pragma unroll 2
    for (int i = 0; i < 32; i += 4) {
      const float4 w0 = *(const float4*)(wp + (i  )*1024);
      const float4 w1 = *(const float4*)(wp + (i+1)*1024);
      const float4 w2 = *(const float4*)(wp + (i+2)*1024);
      const float4 w3 = *(const float4*)(wp + (i+3)*1024);
      const float4 ra = *(const float4*)(rp0 + i);
      const float4 rb = *(const float4*)(rp1 + i);
      const float4 rc = *(const float4*)(rp2 + i);
      const float4 rd = *(const float4*)(rp3 + i);
      #pragma unroll
      for (int u = 0; u < 4; ++u) {
        const float4 w = (u==0)?w0:((u==1)?w1:((u==2)?w2:w3));
        const float r0v = (u==0)?ra.x:((u==1)?ra.y:((u==2)?ra.z:ra.w));
        const float r1v = (u==0)?rb.x:((u==1)?rb.y:((u==2)?rb.z:rb.w));
        const float r2v = (u==0)?rc.x:((u==1)?rc.y:((u==2)?rc.z:rc.w));
        const float r3v = (u==0)?rd.x:((u==1)?rd.y:((u==2)?rd.z:rd.w));
        pacc[0][0] += r0v*w.x; pacc[0][1] += r0v*w.y; pacc[0][2] += r0v*w.z; pacc[0][3] += r0v*w.w;
        pacc[1][0] += r1v*w.x; pacc[1][1] += r1v*w.y; pacc[1][2] += r1v*w.z; pacc[1][3] += r1v*w.w;
        pacc[2][0] += r2v*w.x; pacc[2][1] += r2v*w.y; pacc[2][2] += r2v*w.z; pacc[2][3] += r2v*w.w;
        pacc[3][0] += r3v*w.x; pacc[3][1] += r3v*w.y; pacc[3][2] += r3v*w.z; pacc[3][3] += r3v*w.w;
      }
    }
    #pragma unroll
    for (int v = 0; v < 4; ++v) {
      const float cva = sm[LDS_CF + a_idx*16 + (bg<<2) + v];
      acc[v][0] += cva*pacc[v][0]; acc[v][1] += cva*pacc[v][1];
      acc[v][2] += cva*pacc[v][2]; acc[v][3] += cva*pacc[v][3];
    }

    // ---- narrowing butterfly over the 16 ks-lanes sharing this bg (lane bits 2..5) ----
    float vals[16];
    #pragma unroll
    for (int v = 0; v < 4; ++v) { vals[v*4+0]=acc[v][0]; vals[v*4+1]=acc[v][1];
                                  vals[v*4+2]=acc[v][2]; vals[v*4+3]=acc[v][3]; }
    { const bool hi = (ln & 32) != 0;
      #pragma unroll
      for (int j = 0; j < 8; ++j) { const float kp = hi?vals[j+8]:vals[j], sd = hi?vals[j]:vals[j+8];
        vals[j] = kp + __shfl_xor(sd, 32); } }
    { const bool hi = (ln & 16) != 0;
      #pragma unroll
      for (int j = 0; j < 4; ++j) { const float kp = hi?vals[j+4]:vals[j], sd = hi?vals[j]:vals[j+4];
        vals[j] = kp + __shfl_xor(sd, 16); } }
    { const bool hi = (ln & 8) != 0;
      #pragma unroll
      for (int j = 0; j < 2; ++j) { const float kp = hi?vals[j+2]:vals[j], sd = hi?vals[j]:vals[j+2];
        vals[j] = kp + __shfl_xor(sd, 8); } }
    { const bool hi = (ln & 4) != 0;
      { const float kp = hi?vals[1]:vals[0], sd = hi?vals[0]:vals[1];
        vals[0] = kp + __shfl_xor(sd, 4); } }
    sm[LDS_RED + wv*64 + ln] = vals[0];
    __syncthreads();

    // ---- finalize: wave 0's 64 lanes = the WG's 64 outputs ----
    if (wv == 0) {
      float tot = 0.f;
      #pragma unroll
      for (int w2 = 0; w2 < 16; ++w2) tot += sm[LDS_RED + w2*64 + ln];
      const int j = (((ln>>5)&1)<<3)|(((ln>>4)&1)<<2)|(((ln>>3)&1)<<1)|((ln>>2)&1);
      const int v = j >> 2, m = j & 3;
      const int b = (ln & 3)*4 + v;
      const int mm = (mt<<2) + m;
      const float rec  = tot + KJ0 * sm[LDS_SUMR + b];
      const float rold = sm[LDS_RL + b*RSTR + mm + ((mm>>5)<<2)];
      const float rnew = (1.0f-KALPHA)*rold + KALPHA*fmaxf(rec, 0.0f);
      out[BUMP_OFF + ((bt*16 + b)*TT + t)*NN + mm] = rnew;
    }
    if (t < TT-1) group_barrier(barg, (unsigned)(t+1));
  }
}

// Epilogue: Wd7[n,m]=cos(2pi(n-m)/N) is rank-2 -> r_delta7 = C*cos_m + S*sin_m.
__global__ void __launch_bounds__(256) ring_epi(float* out) {
  const int b = blockIdx.x >> 7, t = blockIdx.x & 127;
  const int n = threadIdx.x;
  const int wv = threadIdx.x >> 6, ln = threadIdx.x & 63;
  __shared__ float l[12];
  const float v = out[BUMP_OFF + (b*TT + t)*NN + n];
  const float ang = (float)n * (6.283185307179586f/256.0f);
  const float cn = cosf(ang), sn = sinf(ang);
  float pc = v*cn, ps = v*sn;
  #pragma unroll
  for (int m = 32; m >= 1; m >>= 1) { pc += __shfl_xor(pc, m); ps += __shfl_xor(ps, m); }
  if (ln == 0) { l[wv] = pc; l[4+wv] = ps; }
  __syncthreads();
  const float C = l[0]+l[1]+l[2]+l[3];
  const float S = l[4]+l[5]+l[6]+l[7];
  const float d7 = C*cn + S*sn;
  float mx = d7;
  #pragma unroll
  for (int m = 32; m >= 1; m >>= 1) mx = fmaxf(mx, __shfl_xor(mx, m));
  if (ln == 0) l[8+wv] = mx;
  __syncthreads();
  mx = fmaxf(fmaxf(l[8], l[9]), fmaxf(l[10], l[11]));
  out[(b*TT + t)*NN + n] = d7/mx;
}

extern "C" void kernel_launch(void* const* d_in, const int* in_sizes, int n_in,
                              void* d_out, int out_size, void* d_ws, size_t ws_size,
                              hipStream_t stream) {
  const float* act = (const float*)d_in[0];   // [64,128,32]
  const float* Wo  = (const float*)d_in[1];   // [256,256]
  const float* Wa  = (const float*)d_in[2];   // [32,256,256]
  float* outp = (float*)d_out;                // [r_history | bump], 4194304 f32
  unsigned* bar = (unsigned*)d_ws;            // 4 groups x 64 uints

  hipLaunchKernelGGL(ring_init, dim3(1), dim3(256), 0, stream, bar);

  // Host-side, stream-free, idempotent: needed for 156KB dynamic LDS.
  (void)hipFuncSetAttribute(reinterpret_cast<const void*>(ring_main),
                            hipFuncAttributeMaxDynamicSharedMemorySize, LDS_FLOATS*4);

  // Plain launch (graph-capture-safe). Co-residency by construction:
  // 156KB LDS -> 1 WG/CU, grid=256 = #CUs; each barrier group needs only
  // its own 64 WGs resident.
  hipLaunchKernelGGL(ring_main, dim3(256), dim3(1024), LDS_FLOATS*4, stream,
                     act, Wo, Wa, outp, bar);

  hipLaunchKernelGGL(ring_epi, dim3(BB*TT), dim3(256), 0, stream, outp);
}

// Round 11
// 1519.464 us; speedup vs baseline: 1.3683x; 1.1184x over previous
//
#include <hip/hip_runtime.h>
#include <math.h>

// Problem constants
#define NN 256
#define AD 32
#define BB 64
#define TT 128
#define KJ0 (-0.1f)
#define KJ1 (0.1f)
#define KALPHA 0.15f
#define BUMP_OFF (BB*TT*NN)   // 2097152 floats; d_out = [r_history | bump]

// LDS layout (float offsets). Total 39888 floats = 159552 B < 160 KiB.
// 1 WG/CU (LDS-forced), 1024 threads = 16 waves = 4 waves/SIMD (r8: occupancy
// 48.9% as designed). r physical index: phys(n) = n + (n>>5)*4.
#define RSTR 284
#define LDS_WM   0        // W_main [i:32][ks:256][m:4] = 32768 (Wa slices)
#define LDS_WW   32768    // W_wo   [n:256][m:4] = 1024  (J1-prescaled Wo)
#define LDS_RL   33792    // r      [b:16][RSTR] = 4544
#define LDS_CF   38336    // coef   [a:32][b:16] = 512
#define LDS_RED  38848    // reduce [w:16][l:64] = 1024
#define LDS_SUMR 39872    // sum_n r[b,n] per local b (16)
#define LDS_FLOATS 39888

// Flag-array barrier (replaces count-RMW barrier; r8 post-mortem: 64
// serialized agent-RMWs/step ~= 5-8us was the dominant non-compute cost).
// flags[grp*64 + wg] on its own 128B line: stores parallel, polls parallel.
// Monotone t-valued flags -> no reset, no ABA. Zeroed by ring_init.
#define FPAD 32                      // 32 uints = 128 B per flag line
#define NFLAGS (4*64*FPAD)           // 8192 uints = 32 KB in d_ws

__global__ void __launch_bounds__(256) ring_init(unsigned* flags) {
  #pragma unroll
  for (int j = 0; j < 32; ++j) flags[j*256 + threadIdx.x] = 0u;
}

// 256 WGs: bid = bt*64 + mt (bt: 16 batches, mt: 4 outputs). 1024 threads:
// wv=tid>>6 (16 waves), ln=tid&63; bg=ln&3 (b-quad), ks=wv*16+(ln>>2) in
// 0..255: action a=ks>>3, n-slice [sub*32, sub*32+32), sub=ks&7 -> one action
// coefficient per thread slice, applied once after the inner loop.
__global__ void __launch_bounds__(1024) ring_main(const float* __restrict__ act,
                                                  const float* __restrict__ Wo,
                                                  const float* __restrict__ Wa,
                                                  float* __restrict__ out,
                                                  unsigned* __restrict__ flags) {
  extern __shared__ float sm[];
  const int tid = threadIdx.x;
  const int bid = blockIdx.x;
  const int bt = bid >> 6;
  const int mt = bid & 63;
  const int wv = tid >> 6;
  const int ln = tid & 63;
  const int bg = ln & 3;
  const int ks = wv*16 + (ln >> 2);     // 0..255
  const int a_idx = ks >> 3;
  const int sub = ks & 7;
  unsigned* myflag = flags + (bt*64 + mt)*FPAD;

  // ---- one-time: gather Wa slices, layout [i:32][ks:256][m:4] so the wave's
  // 16 consecutive ks read 256 contiguous bytes (conflict-free) ----
  #pragma unroll
  for (int j = 0; j < 8; ++j) {
    const int flat = j*1024 + tid;      // = i*256 + kk
    const int i = flat >> 8, kk = flat & 255;
    const int a = kk >> 3, n = ((kk & 7) << 5) + i;
    const float4 w = *(const float4*)(Wa + (a*NN + n)*NN + (mt<<2));
    *(float4*)(&sm[LDS_WM + (flat<<2)]) = w;
  }
  if (tid < 256) { // Wo slice, pre-scaled by J1
    const float4 w = *(const float4*)(Wo + tid*NN + (mt<<2));
    float4 s; s.x = w.x*KJ1; s.y = w.y*KJ1; s.z = w.z*KJ1; s.w = w.w*KJ1;
    *(float4*)(&sm[LDS_WW + (tid<<2)]) = s;
  }

  // ---- t=0 state: initial bump (identical for all batches); wave wv owns b=wv ----
  {
    const int c = ln;
    float v0[4]; float ss = 0.f, sv = 0.f;
    const float denom = 2.0f*25.6f*25.6f;
    #pragma unroll
    for (int u = 0; u < 4; ++u) {
      const float fn = (float)(c*4 + u);
      const float d = fabsf(fn - 128.0f);
      const float dist = fminf(d, 256.0f - d);
      const float e = expf(-(dist*dist)/denom);
      v0[u] = e; ss += e*e; sv += e;
    }
    ss += __shfl_xor(ss,32); ss += __shfl_xor(ss,16); ss += __shfl_xor(ss,8);
    ss += __shfl_xor(ss,4);  ss += __shfl_xor(ss,2);  ss += __shfl_xor(ss,1);
    sv += __shfl_xor(sv,32); sv += __shfl_xor(sv,16); sv += __shfl_xor(sv,8);
    sv += __shfl_xor(sv,4);  sv += __shfl_xor(sv,2);  sv += __shfl_xor(sv,1);
    const float inv = 1.0f/sqrtf(ss);
    float4 o; o.x = v0[0]*inv; o.y = v0[1]*inv; o.z = v0[2]*inv; o.w = v0[3]*inv;
    *(float4*)(&sm[LDS_RL + wv*RSTR + (c<<2) + ((c>>3)<<2)]) = o;  // phys(4c)
    if (c == 0) sm[LDS_SUMR + wv] = sv*inv;
  }

  for (int t = 0; t < TT; ++t) {
    if (t > 0) {
      // ---- wait: all 64 group flags >= t (r(t-1) complete). Wave 0's 64
      // lanes poll 64 flags in parallel; bounded 10 ms -> fast wrong answer,
      // never a hang (10ms ~ 40x worst profiled-replay wait seen in r6). ----
      if (wv == 0) {
        unsigned* f = flags + (bt*64 + ln)*FPAD;
        const unsigned long long t0 = __builtin_amdgcn_s_memrealtime();  // 100 MHz
        for (;;) {
          const int v = (int)__hip_atomic_load(f, __ATOMIC_RELAXED, __HIP_MEMORY_SCOPE_AGENT);
          if (v >= t) break;
          __builtin_amdgcn_s_sleep(1);
          if (__builtin_amdgcn_s_memrealtime() - t0 > 1000000ull) break;  // 10 ms
        }
        (void)__hip_atomic_load(f, __ATOMIC_ACQUIRE, __HIP_MEMORY_SCOPE_AGENT);
      }
      __syncthreads();   // transitive hb: acquire by wave0 -> all waves

      // ---- stage r(t-1): wave wv stages batch row b=wv from out ----
      const float* src = out + BUMP_OFF + (((bt*16 + wv)*TT) + (t-1))*NN + (ln<<2);
      const float4 x = *(const float4*)src;
      *(float4*)(&sm[LDS_RL + wv*RSTR + (ln<<2) + ((ln>>3)<<2)]) = x;
      float s = x.x + x.y + x.z + x.w;
      s += __shfl_xor(s,32); s += __shfl_xor(s,16); s += __shfl_xor(s,8);
      s += __shfl_xor(s,4);  s += __shfl_xor(s,2);  s += __shfl_xor(s,1);
      if (ln == 0) sm[LDS_SUMR + wv] = s;
    }
    // ---- stage action coefficients [a][b16] ----
    if (tid < 512) {
      const int b0 = tid >> 5, aa = tid & 31;
      sm[LDS_CF + aa*16 + b0] = act[(bt*16 + b0)*(TT*AD) + t*AD + aa];
    }
    __syncthreads();

    // ---- compute acc[v][m] for this thread's 4b x 4m tile ----
    float acc[4][4];
    #pragma unroll
    for (int v = 0; v < 4; ++v) { acc[v][0]=0.f; acc[v][1]=0.f; acc[v][2]=0.f; acc[v][3]=0.f; }

    // Wo pass (J1 pre-baked): single n = ks per thread
    {
      const float4 w = *(const float4*)&sm[LDS_WW + (ks<<2)];
      const int np = ks + ((ks>>5)<<2);   // phys(ks)
      #pragma unroll
      for (int v = 0; v < 4; ++v) {
        const float rv = sm[LDS_RL + ((bg<<2)+v)*RSTR + np];
        acc[v][0] += rv*w.x; acc[v][1] += rv*w.y; acc[v][2] += rv*w.z; acc[v][3] += rv*w.w;
      }
    }

    // Main pass: 32-n slice of action a_idx; coef applied once at the end
    float pacc[4][4];
    #pragma unroll
    for (int v = 0; v < 4; ++v) { pacc[v][0]=0.f; pacc[v][1]=0.f; pacc[v][2]=0.f; pacc[v][3]=0.f; }
    const float* wp  = &sm[LDS_WM + (ks<<2)];          // stride 1024 per i
    const float* rp0 = &sm[LDS_RL + (bg<<2)*RSTR + sub*36];  // phys(sub*32)=36*sub
    const float* rp1 = rp0 + RSTR;
    const float* rp2 = rp1 + RSTR;
    const float* rp3 = rp2 + RSTR;
    #pragma unroll 2
    for (int i = 0; i < 32; i += 4) {
      const float4 w0 = *(const float4*)(wp + (i  )*1024);
      const float4 w1 = *(const float4*)(wp + (i+1)*1024);
      const float4 w2 = *(const float4*)(wp + (i+2)*1024);
      const float4 w3 = *(const float4*)(wp + (i+3)*1024);
      const float4 ra = *(const float4*)(rp0 + i);
      const float4 rb = *(const float4*)(rp1 + i);
      const float4 rc = *(const float4*)(rp2 + i);
      const float4 rd = *(const float4*)(rp3 + i);
      #pragma unroll
      for (int u = 0; u < 4; ++u) {
        const float4 w = (u==0)?w0:((u==1)?w1:((u==2)?w2:w3));
        const float r0v = (u==0)?ra.x:((u==1)?ra.y:((u==2)?ra.z:ra.w));
        const float r1v = (u==0)?rb.x:((u==1)?rb.y:((u==2)?rb.z:rb.w));
        const float r2v = (u==0)?rc.x:((u==1)?rc.y:((u==2)?rc.z:rc.w));
        const float r3v = (u==0)?rd.x:((u==1)?rd.y:((u==2)?rd.z:rd.w));
        pacc[0][0] += r0v*w.x; pacc[0][1] += r0v*w.y; pacc[0][2] += r0v*w.z; pacc[0][3] += r0v*w.w;
        pacc[1][0] += r1v*w.x; pacc[1][1] += r1v*w.y; pacc[1][2] += r1v*w.z; pacc[1][3] += r1v*w.w;
        pacc[2][0] += r2v*w.x; pacc[2][1] += r2v*w.y; pacc[2][2] += r2v*w.z; pacc[2][3] += r2v*w.w;
        pacc[3][0] += r3v*w.x; pacc[3][1] += r3v*w.y; pacc[3][2] += r3v*w.z; pacc[3][3] += r3v*w.w;
      }
    }
    #pragma unroll
    for (int v = 0; v < 4; ++v) {
      const float cva = sm[LDS_CF + a_idx*16 + (bg<<2) + v];
      acc[v][0] += cva*pacc[v][0]; acc[v][1] += cva*pacc[v][1];
      acc[v][2] += cva*pacc[v][2]; acc[v][3] += cva*pacc[v][3];
    }

    // ---- narrowing butterfly over the 16 ks-lanes sharing this bg (lane bits 2..5) ----
    float vals[16];
    #pragma unroll
    for (int v = 0; v < 4; ++v) { vals[v*4+0]=acc[v][0]; vals[v*4+1]=acc[v][1];
                                  vals[v*4+2]=acc[v][2]; vals[v*4+3]=acc[v][3]; }
    { const bool hi = (ln & 32) != 0;
      #pragma unroll
      for (int j = 0; j < 8; ++j) { const float kp = hi?vals[j+8]:vals[j], sd = hi?vals[j]:vals[j+8];
        vals[j] = kp + __shfl_xor(sd, 32); } }
    { const bool hi = (ln & 16) != 0;
      #pragma unroll
      for (int j = 0; j < 4; ++j) { const float kp = hi?vals[j+4]:vals[j], sd = hi?vals[j]:vals[j+4];
        vals[j] = kp + __shfl_xor(sd, 16); } }
    { const bool hi = (ln & 8) != 0;
      #pragma unroll
      for (int j = 0; j < 2; ++j) { const float kp = hi?vals[j+2]:vals[j], sd = hi?vals[j]:vals[j+2];
        vals[j] = kp + __shfl_xor(sd, 8); } }
    { const bool hi = (ln & 4) != 0;
      { const float kp = hi?vals[1]:vals[0], sd = hi?vals[0]:vals[1];
        vals[0] = kp + __shfl_xor(sd, 4); } }
    sm[LDS_RED + wv*64 + ln] = vals[0];
    __syncthreads();

    // ---- finalize: wave 0's 64 lanes = the WG's 64 outputs ----
    if (wv == 0) {
      float tot = 0.f;
      #pragma unroll
      for (int w2 = 0; w2 < 16; ++w2) tot += sm[LDS_RED + w2*64 + ln];
      const int j = (((ln>>5)&1)<<3)|(((ln>>4)&1)<<2)|(((ln>>3)&1)<<1)|((ln>>2)&1);
      const int v = j >> 2, m = j & 3;
      const int b = (ln & 3)*4 + v;
      const int mm = (mt<<2) + m;
      const float rec  = tot + KJ0 * sm[LDS_SUMR + b];
      const float rold = sm[LDS_RL + b*RSTR + mm + ((mm>>5)<<2)];
      const float rnew = (1.0f-KALPHA)*rold + KALPHA*fmaxf(rec, 0.0f);
      out[BUMP_OFF + ((bt*16 + b)*TT + t)*NN + mm] = rnew;
    }
    if (t < TT-1) {
      __syncthreads();   // wave0's r_new stores drained (vmcnt) before release
      if (tid == 0) {
        __hip_atomic_store(myflag, (unsigned)(t+1),
                           __ATOMIC_RELEASE, __HIP_MEMORY_SCOPE_AGENT);
      }
    }
  }
}

// Epilogue: Wd7[n,m]=cos(2pi(n-m)/N) is rank-2 -> r_delta7 = C*cos_m + S*sin_m.
__global__ void __launch_bounds__(256) ring_epi(float* out) {
  const int b = blockIdx.x >> 7, t = blockIdx.x & 127;
  const int n = threadIdx.x;
  const int wv = threadIdx.x >> 6, ln = threadIdx.x & 63;
  __shared__ float l[12];
  const float v = out[BUMP_OFF + (b*TT + t)*NN + n];
  const float ang = (float)n * (6.283185307179586f/256.0f);
  const float cn = cosf(ang), sn = sinf(ang);
  float pc = v*cn, ps = v*sn;
  #pragma unroll
  for (int m = 32; m >= 1; m >>= 1) { pc += __shfl_xor(pc, m); ps += __shfl_xor(ps, m); }
  if (ln == 0) { l[wv] = pc; l[4+wv] = ps; }
  __syncthreads();
  const float C = l[0]+l[1]+l[2]+l[3];
  const float S = l[4]+l[5]+l[6]+l[7];
  const float d7 = C*cn + S*sn;
  float mx = d7;
  #pragma unroll
  for (int m = 32; m >= 1; m >>= 1) mx = fmaxf(mx, __shfl_xor(mx, m));
  if (ln == 0) l[8+wv] = mx;
  __syncthreads();
  mx = fmaxf(fmaxf(l[8], l[9]), fmaxf(l[10], l[11]));
  out[(b*TT + t)*NN + n] = d7/mx;
}

extern "C" void kernel_launch(void* const* d_in, const int* in_sizes, int n_in,
                              void* d_out, int out_size, void* d_ws, size_t ws_size,
                              hipStream_t stream) {
  const float* act = (const float*)d_in[0];   // [64,128,32]
  const float* Wo  = (const float*)d_in[1];   // [256,256]
  const float* Wa  = (const float*)d_in[2];   // [32,256,256]
  float* outp = (float*)d_out;                // [r_history | bump], 4194304 f32
  unsigned* flags = (unsigned*)d_ws;          // 4 groups x 64 flags x 128B

  hipLaunchKernelGGL(ring_init, dim3(1), dim3(256), 0, stream, flags);

  // Host-side, stream-free, idempotent: needed for 156KB dynamic LDS.
  (void)hipFuncSetAttribute(reinterpret_cast<const void*>(ring_main),
                            hipFuncAttributeMaxDynamicSharedMemorySize, LDS_FLOATS*4);

  // Plain launch (graph-capture-safe). Co-residency by construction:
  // 156KB LDS -> 1 WG/CU, grid=256 = #CUs; each barrier group needs only
  // its own 64 WGs resident.
  hipLaunchKernelGGL(ring_main, dim3(256), dim3(1024), LDS_FLOATS*4, stream,
                     act, Wo, Wa, outp, flags);

  hipLaunchKernelGGL(ring_epi, dim3(BB*TT), dim3(256), 0, stream, outp);
}